// Round 7
// baseline (748.806 us; speedup 1.0000x reference)
//
#include <hip/hip_runtime.h>
#include <hip/hip_bf16.h>

typedef __attribute__((ext_vector_type(4))) float f32x4;
typedef __attribute__((ext_vector_type(4))) unsigned int u32x4;

// Problem constants
static constexpr int Bb = 64;
static constexpr int Tt = 2048;
static constexpr int Ee = 1024;
static constexpr int Hh = 1024;
static constexpr int ATTN_N = Bb * Ee;      // 65536
static constexpr int PROB_N = Bb * Tt;      // 131072

__device__ inline unsigned short f2bf(float f) {
    __hip_bfloat16 h = __float2bfloat16(f);  // RNE
    return __builtin_bit_cast(unsigned short, h);
}

__device__ inline void gload_lds16(const unsigned short* g, unsigned short* l) {
    __builtin_amdgcn_global_load_lds(
        (const __attribute__((address_space(1))) void*)g,
        (__attribute__((address_space(3))) void*)l,
        16, 0, 0);
}

// ---------------------------------------------------------------------------
// K0a: W_enc [E][H] fp32  ->  W16T [H][E] bf16 (transposed)
// ---------------------------------------------------------------------------
__global__ void wtrans_kernel(const float* __restrict__ w_enc,
                              unsigned short* __restrict__ w16t) {
    __shared__ float tile[32][33];
    const int bx = blockIdx.x & 31;   // h tile
    const int by = blockIdx.x >> 5;   // e tile
    const int tx = threadIdx.x & 31;
    const int ty = threadIdx.x >> 5;  // 0..7
#pragma unroll
    for (int j = 0; j < 4; ++j) {
        int e = by * 32 + ty + j * 8;
        int h = bx * 32 + tx;
        tile[ty + j * 8][tx] = w_enc[e * Hh + h];
    }
    __syncthreads();
#pragma unroll
    for (int j = 0; j < 4; ++j) {
        int h = bx * 32 + ty + j * 8;
        int e = by * 32 + tx;
        w16t[h * Ee + e] = f2bf(tile[tx][ty + j * 8]);
    }
}

// ---------------------------------------------------------------------------
// K0b: ddec[b][h] = dec[b]·W_dec[:,h] + b_dec[h] + b_enc[h]   (fp32 exact)
// ---------------------------------------------------------------------------
__global__ void ddec_kernel(const float* __restrict__ dec,
                            const float* __restrict__ w_dec,
                            const float* __restrict__ b_dec,
                            const float* __restrict__ b_enc,
                            float* __restrict__ ddec) {
    const int b = blockIdx.y;
    const int h = blockIdx.x * 256 + threadIdx.x;
    float acc = b_dec[h] + b_enc[h];
    const float* dr = dec + b * Ee;
#pragma unroll 4
    for (int e = 0; e < Ee; ++e) {
        acc += dr[e] * w_dec[e * Hh + h];
    }
    ddec[b * Hh + h] = acc;
}

// ---------------------------------------------------------------------------
// K1: fused  scores[b,t] += sum_h tanh(enc·W_enc + ddec) * W_out[h]
// 256x256 tile, BK=64, 8 waves (2M x 4N, per-wave 128x64).
// 4 phases per K-tile: {ds_read frags || staging issue} -> barrier ->
//   lgkmcnt(0) -> setprio(1) 16xMFMA setprio(0) -> barrier.
// Pipeline: A (fp32 enc, HBM) prefetched TWO K-tiles ahead into ping-pong
// reg sets (compile-time parity via unroll-by-2), ds_written one tile ahead.
// COUNTED vmcnt: phase D waits vmcnt(8) (B's 4 gload_lds done, A's 8 loads
// still in flight); phase C's implicit reg-dep wait is vmcnt(12). No
// vmcnt(0) in the steady-state loop (T4).
// launch_bounds(512, 1): R6's (512,2) capped VGPR at 128 and spilled ~half
// the accumulator to scratch (WRITE_SIZE 32->113 MB). LDS is 128 KB so only
// 1 block/CU fits regardless -- declaring 1 costs nothing, frees 256 VGPRs.
// ---------------------------------------------------------------------------
__global__ __launch_bounds__(512, 1) void gemm_score_kernel(
    const float* __restrict__ enc, const unsigned short* __restrict__ w16t,
    const float* __restrict__ ddec, const float* __restrict__ w_out,
    float* __restrict__ scores) {
    __shared__ unsigned short As[2][256 * 64];
    __shared__ unsigned short Bs[2][256 * 64];

    const int tid = threadIdx.x;
    const int lane = tid & 63;
    const int wid = tid >> 6;          // 0..7
    const int wm = wid >> 2;           // 0..1
    const int wn = wid & 3;            // 0..3
    const int lr = lane & 15;
    const int lg = lane >> 4;          // 0..3

    // XCD-aware swizzle (8 XCDs). 512 m-tiles x 4 n-tiles = 2048 blocks.
    const int g = blockIdx.x;
    const int xcd = g & 7;
    const int slot = g >> 3;                    // 0..255
    const int ntile = slot & 3;                 // 0..3
    const int mtile = xcd * 64 + (slot >> 2);   // 0..511
    const int m0 = mtile * 256;
    const int n0 = ntile * 256;
    const int bidx = m0 >> 11;         // 256-row tile never straddles a batch

    // A staging map: thread t -> rows (t>>3)+64*ci, 16B k-slot (t&7)
    const int ar = tid >> 3;           // 0..63
    const int as = tid & 7;            // 0..7

    f32x4 rsA[8], rsB[8];

    auto loadA = [&](int kt, f32x4 (&rs)[8]) {
        const float* src = enc + (size_t)(m0 + ar) * Ee + kt * 64 + as * 8;
#pragma unroll
        for (int ci = 0; ci < 4; ++ci) {
            rs[ci * 2]     = *reinterpret_cast<const f32x4*>(src + (size_t)(64 * ci) * Ee);
            rs[ci * 2 + 1] = *reinterpret_cast<const f32x4*>(src + (size_t)(64 * ci) * Ee + 4);
        }
    };
    auto writeA = [&](int db, f32x4 (&rs)[8]) {
        char* abase = (char*)&As[db][0];
#pragma unroll
        for (int ci = 0; ci < 4; ++ci) {
            int r = ar + 64 * ci;
            u32x4 w;
            w.x = (unsigned)f2bf(rs[2 * ci].x) | ((unsigned)f2bf(rs[2 * ci].y) << 16);
            w.y = (unsigned)f2bf(rs[2 * ci].z) | ((unsigned)f2bf(rs[2 * ci].w) << 16);
            w.z = (unsigned)f2bf(rs[2 * ci + 1].x) | ((unsigned)f2bf(rs[2 * ci + 1].y) << 16);
            w.w = (unsigned)f2bf(rs[2 * ci + 1].z) | ((unsigned)f2bf(rs[2 * ci + 1].w) << 16);
            *reinterpret_cast<u32x4*>(abase + r * 128 + ((as * 16) ^ ((r & 7) << 4))) = w;
        }
    };
    // B direct-to-LDS: wave wid, call c writes LDS rows (wid*4+c)*8..+8 linearly;
    // lane l covers row +(l>>3), slot (l&7). Source slot pre-swizzled:
    // LDS slot s at row r holds global slot s^(r&7), r&7 == l>>3.
    auto stageB = [&](int kt, int db) {
        const int sg = (lane & 7) ^ (lane >> 3);
#pragma unroll
        for (int c = 0; c < 4; ++c) {
            int rr = (wid * 4 + c) * 8 + (lane >> 3);
            const unsigned short* src = w16t + (size_t)(n0 + rr) * Ee + kt * 64 + sg * 8;
            gload_lds16(src, &Bs[db][(wid * 4 + c) * 512]);
        }
    };

    // accumulators init with ddec
    f32x4 acc[8][4];
#pragma unroll
    for (int ni = 0; ni < 4; ++ni) {
        float dv = ddec[bidx * Hh + n0 + wn * 64 + ni * 16 + lr];
#pragma unroll
        for (int mi = 0; mi < 8; ++mi) {
            acc[mi][ni].x = dv; acc[mi][ni].y = dv;
            acc[mi][ni].z = dv; acc[mi][ni].w = dv;
        }
    }

    u32x4 af[4], bf[4];
    auto readB4 = [&](int db, int kh) {
        const char* bbase = (const char*)&Bs[db][0];
        const int kb = kh * 64 + lg * 16;
#pragma unroll
        for (int ni = 0; ni < 4; ++ni) {
            int r = wn * 64 + ni * 16 + lr;
            bf[ni] = *reinterpret_cast<const u32x4*>(bbase + r * 128 + (kb ^ ((r & 7) << 4)));
        }
    };
    auto readA4 = [&](int db, int kh, int mib) {
        const char* abase = (const char*)&As[db][0];
        const int kb = kh * 64 + lg * 16;
#pragma unroll
        for (int k = 0; k < 4; ++k) {
            int r = wm * 128 + (mib + k) * 16 + lr;
            af[k] = *reinterpret_cast<const u32x4*>(abase + r * 128 + (kb ^ ((r & 7) << 4)));
        }
    };
    auto mfma16 = [&](int mib) {
        __builtin_amdgcn_s_setprio(1);
#pragma unroll
        for (int k = 0; k < 4; ++k)
#pragma unroll
            for (int ni = 0; ni < 4; ++ni)
                asm("v_mfma_f32_16x16x32_bf16 %0, %1, %2, %0"
                    : "+v"(acc[mib + k][ni])
                    : "v"(af[k]), "v"(bf[ni]));
        __builtin_amdgcn_s_setprio(0);
    };

#define BARRIER() do { asm volatile("" ::: "memory"); \
    __builtin_amdgcn_s_barrier(); asm volatile("" ::: "memory"); } while (0)
#define LGKM0() asm volatile("s_waitcnt lgkmcnt(0)" ::: "memory")

    // ---- prologue: tile 0 into buffer 0; tile 1 A-loads in flight ----
    loadA(0, rsA);
    stageB(0, 0);
    writeA(0, rsA);            // implicit wait: loadA(0) done (stageB stays)
    loadA(1, rsB);
    asm volatile("s_waitcnt vmcnt(8)" ::: "memory");  // stageB(0) complete
    LGKM0();
    BARRIER();

#pragma unroll 1
    for (int tt = 0; tt < 16; tt += 2) {
#pragma unroll
        for (int p = 0; p < 2; ++p) {   // p is compile-time after unroll
            const int t = tt + p;
            f32x4 (&rs_next)[8] = (p == 0) ? rsA : rsB;  // receives tile t+2
            f32x4 (&rs_cur)[8]  = (p == 0) ? rsB : rsA;  // holds tile t+1
            // ---- phase A: kh=0, mi 0..3; issue next-tile staging ----
            readB4(p, 0);
            readA4(p, 0, 0);
            if (t < 15) stageB(t + 1, p ^ 1);   // 4 gload_lds
            if (t < 14) loadA(t + 2, rs_next);  // 8 dwordx4 (newest)
            BARRIER(); LGKM0();
            mfma16(0);
            BARRIER();
            // ---- phase B: kh=0, mi 4..7 ----
            readA4(p, 0, 4);
            BARRIER(); LGKM0();
            mfma16(4);
            BARRIER();
            // ---- phase C: kh=1, mi 0..3; A ds_write (tile t+1) ----
            readB4(p, 1);
            readA4(p, 1, 0);
            if (t < 15) writeA(p ^ 1, rs_cur);  // implicit vmcnt(12)
            BARRIER(); LGKM0();
            mfma16(0);
            BARRIER();
            // ---- phase D: kh=1, mi 4..7; counted B-publication wait ----
            readA4(p, 1, 4);
            if (t < 14) {
                asm volatile("s_waitcnt vmcnt(8)" ::: "memory"); // B done, A in flight
            } else if (t == 14) {
                asm volatile("s_waitcnt vmcnt(0)" ::: "memory"); // tail drain
            }
            BARRIER(); LGKM0();
            mfma16(4);
            BARRIER();
        }
    }

    // drain MFMA pipe before VALU reads of acc
    asm volatile("s_nop 7\n\ts_nop 7\n\ts_nop 7" ::: );

    float wout[4];
#pragma unroll
    for (int ni = 0; ni < 4; ++ni)
        wout[ni] = w_out[n0 + wn * 64 + ni * 16 + lr];

#pragma unroll
    for (int mi = 0; mi < 8; ++mi) {
#pragma unroll
        for (int i = 0; i < 4; ++i) {
            float s = 0.f;
#pragma unroll
            for (int ni = 0; ni < 4; ++ni) {
                float x = (i == 0) ? acc[mi][ni].x : (i == 1) ? acc[mi][ni].y
                           : (i == 2) ? acc[mi][ni].z : acc[mi][ni].w;
                // tanh(x) = 1 - 2/(e^{2x}+1)  (stable at +/-inf)
                float t = 1.f - 2.f / (__expf(2.f * x) + 1.f);
                s += t * wout[ni];
            }
            s += __shfl_xor(s, 1);
            s += __shfl_xor(s, 2);
            s += __shfl_xor(s, 4);
            s += __shfl_xor(s, 8);
            if (lr == 0) {
                int row = m0 + wm * 128 + mi * 16 + 4 * lg + i;
                atomicAdd(&scores[row], s);
            }
        }
    }
#undef BARRIER
#undef LGKM0
}

// ---------------------------------------------------------------------------
// K2: masked softmax over T per batch row, in place (scores -> probs).
// ---------------------------------------------------------------------------
__global__ __launch_bounds__(256) void softmax_kernel(float* __restrict__ sc,
                                                      const int* __restrict__ mask) {
    __shared__ float red[256];
    const int b = blockIdx.x;
    const int tid = threadIdx.x;
    float* row = sc + b * Tt;
    const int* mrow = mask + b * Tt;

    float v[8];
    float mx = -3.0e38f;
#pragma unroll
    for (int j = 0; j < 8; ++j) {
        int t = tid + j * 256;
        float s = row[t];
        v[j] = (mrow[t] == 0) ? -1.0e9f : s;
        mx = fmaxf(mx, v[j]);
    }
    red[tid] = mx;
    __syncthreads();
    for (int off = 128; off > 0; off >>= 1) {
        if (tid < off) red[tid] = fmaxf(red[tid], red[tid + off]);
        __syncthreads();
    }
    mx = red[0];
    __syncthreads();

    float p[8];
    float sum = 0.f;
#pragma unroll
    for (int j = 0; j < 8; ++j) {
        p[j] = __expf(v[j] - mx);   // masked -> exp(~-1e9) == 0 exactly
        sum += p[j];
    }
    red[tid] = sum;
    __syncthreads();
    for (int off = 128; off > 0; off >>= 1) {
        if (tid < off) red[tid] += red[tid + off];
        __syncthreads();
    }
    float inv = 1.f / red[0];
#pragma unroll
    for (int j = 0; j < 8; ++j)
        row[tid + j * 256] = p[j] * inv;
}

// ---------------------------------------------------------------------------
// K3: attn[b][e] = sum_t probs[b][t] * enc[b][t][e]   (memory bound)
// ---------------------------------------------------------------------------
__global__ __launch_bounds__(256) void attn_kernel(const float* __restrict__ enc,
                                                   const float* __restrict__ probs,
                                                   float* __restrict__ attn) {
    __shared__ float pr[128];
    const int b = blockIdx.y;
    const int tc = blockIdx.x;        // 0..15  t-chunk of 128
    const int tid = threadIdx.x;
    if (tid < 128) pr[tid] = probs[b * Tt + tc * 128 + tid];
    __syncthreads();

    const int e0 = tid * 4;
    f32x4 acc; acc.x = 0.f; acc.y = 0.f; acc.z = 0.f; acc.w = 0.f;
    const float* base = enc + (size_t)b * Tt * Ee + (size_t)tc * 128 * Ee + e0;
#pragma unroll 4
    for (int t = 0; t < 128; ++t) {
        f32x4 vv = *reinterpret_cast<const f32x4*>(base + (size_t)t * Ee);
        float pw = pr[t];
        acc.x += pw * vv.x; acc.y += pw * vv.y;
        acc.z += pw * vv.z; acc.w += pw * vv.w;
    }
    atomicAdd(&attn[b * Ee + e0 + 0], acc.x);
    atomicAdd(&attn[b * Ee + e0 + 1], acc.y);
    atomicAdd(&attn[b * Ee + e0 + 2], acc.z);
    atomicAdd(&attn[b * Ee + e0 + 3], acc.w);
}

// ---------------------------------------------------------------------------
extern "C" void kernel_launch(void* const* d_in, const int* in_sizes, int n_in,
                              void* d_out, int out_size, void* d_ws, size_t ws_size,
                              hipStream_t stream) {
    const float* enc      = (const float*)d_in[0];
    const float* dec      = (const float*)d_in[1];
    const int*   inp_mask = (const int*)d_in[2];
    const float* W_enc    = (const float*)d_in[3];
    const float* b_enc    = (const float*)d_in[4];
    const float* W_dec    = (const float*)d_in[5];
    const float* b_dec    = (const float*)d_in[6];
    const float* W_out    = (const float*)d_in[7];
    // b_out (d_in[8]) cancels in softmax and is otherwise unused.

    float* attn   = (float*)d_out;            // [64][1024]
    float* scores = (float*)d_out + ATTN_N;   // [64][2048], becomes probs

    unsigned short* w16t = (unsigned short*)d_ws;  // 2 MB bf16 W_enc^T
    // ddec [64][1024] fp32 lives temporarily in the attn region of d_out.
    float* ddec = attn;

    // zero score accumulator
    hipMemsetAsync(scores, 0, (size_t)PROB_N * sizeof(float), stream);

    wtrans_kernel<<<dim3(1024), 256, 0, stream>>>(W_enc, w16t);
    ddec_kernel<<<dim3(4, 64), 256, 0, stream>>>(dec, W_dec, b_dec, b_enc, ddec);
    gemm_score_kernel<<<dim3(2048), 512, 0, stream>>>(enc, w16t, ddec, W_out, scores);

    // attn region done serving as ddec; zero it for atomic accumulation
    hipMemsetAsync(attn, 0, (size_t)ATTN_N * sizeof(float), stream);

    softmax_kernel<<<dim3(64), 256, 0, stream>>>(scores, inp_mask);
    attn_kernel<<<dim3(16, 64), 256, 0, stream>>>(enc, scores, attn);
}

// Round 9
// 643.013 us; speedup vs baseline: 1.1645x; 1.1645x over previous
//
#include <hip/hip_runtime.h>
#include <hip/hip_bf16.h>

typedef __attribute__((ext_vector_type(4))) float f32x4;
typedef __attribute__((ext_vector_type(4))) unsigned int u32x4;

// Problem constants
static constexpr int Bb = 64;
static constexpr int Tt = 2048;
static constexpr int Ee = 1024;
static constexpr int Hh = 1024;
static constexpr int ATTN_N = Bb * Ee;      // 65536
static constexpr int PROB_N = Bb * Tt;      // 131072

__device__ inline unsigned short f2bf(float f) {
    __hip_bfloat16 h = __float2bfloat16(f);  // RNE
    return __builtin_bit_cast(unsigned short, h);
}

__device__ inline void gload_lds16(const unsigned short* g, unsigned short* l) {
    __builtin_amdgcn_global_load_lds(
        (const __attribute__((address_space(1))) void*)g,
        (__attribute__((address_space(3))) void*)l,
        16, 0, 0);
}

// ---------------------------------------------------------------------------
// K0a: W_enc [E][H] fp32  ->  W16T [H][E] bf16 (transposed)
// ---------------------------------------------------------------------------
__global__ void wtrans_kernel(const float* __restrict__ w_enc,
                              unsigned short* __restrict__ w16t) {
    __shared__ float tile[32][33];
    const int bx = blockIdx.x & 31;   // h tile
    const int by = blockIdx.x >> 5;   // e tile
    const int tx = threadIdx.x & 31;
    const int ty = threadIdx.x >> 5;  // 0..7
#pragma unroll
    for (int j = 0; j < 4; ++j) {
        int e = by * 32 + ty + j * 8;
        int h = bx * 32 + tx;
        tile[ty + j * 8][tx] = w_enc[e * Hh + h];
    }
    __syncthreads();
#pragma unroll
    for (int j = 0; j < 4; ++j) {
        int h = bx * 32 + ty + j * 8;
        int e = by * 32 + tx;
        w16t[h * Ee + e] = f2bf(tile[tx][ty + j * 8]);
    }
}

// ---------------------------------------------------------------------------
// K0b: ddec[b][h] = dec[b]·W_dec[:,h] + b_dec[h] + b_enc[h]   (fp32 exact)
// ---------------------------------------------------------------------------
__global__ void ddec_kernel(const float* __restrict__ dec,
                            const float* __restrict__ w_dec,
                            const float* __restrict__ b_dec,
                            const float* __restrict__ b_enc,
                            float* __restrict__ ddec) {
    const int b = blockIdx.y;
    const int h = blockIdx.x * 256 + threadIdx.x;
    float acc = b_dec[h] + b_enc[h];
    const float* dr = dec + b * Ee;
#pragma unroll 4
    for (int e = 0; e < Ee; ++e) {
        acc += dr[e] * w_dec[e * Hh + h];
    }
    ddec[b * Hh + h] = acc;
}

// ---------------------------------------------------------------------------
// K1: fused  scores[b,t] += sum_h tanh(enc·W_enc + ddec) * W_out[h]
// 256x256 tile, BK=64, 8 waves (2M x 4N, per-wave 128x64).
// 4 phases per K-tile: {ds_read frags || staging issue} -> barrier ->
//   lgkmcnt(0) -> setprio(1) 16xMFMA setprio(0) -> barrier.
//
// Pipeline (R9 = R8 + WAR fences): SINGLE A-prefetch register set rs[8].
//   - loadA(t+2) issued at tile t phase D AFTER "BARRIER; LGKM0" so the
//     ds_writes of writeA (which READ rs) are fully drained before the
//     global loads overwrite rs.  R8 issued loadA immediately after writeA:
//     WAR between LDS-pipe operand read and VMEM writeback -> intermittent
//     A-tile corruption (absmax 1.16e-2).  Same fence added in prologue.
//   - counted waits: writeA's implicit reg-dep wait = vmcnt(4) (A(t+1)
//     retired, B(t+1)'s 4 gload_lds stay in flight); after loadA(t+2),
//     explicit vmcnt(8) retires B(t+1) only. No vmcnt(0) in steady state.
// B staged direct via global_load_lds (linear LDS dest, inverse-swizzled
// per-lane global source). XOR-swizzled LDS reads + XCD block swizzle
// carried over unchanged (verified R3-R7).
// ---------------------------------------------------------------------------
__global__ __launch_bounds__(512, 1) void gemm_score_kernel(
    const float* __restrict__ enc, const unsigned short* __restrict__ w16t,
    const float* __restrict__ ddec, const float* __restrict__ w_out,
    float* __restrict__ scores) {
    __shared__ unsigned short As[2][256 * 64];
    __shared__ unsigned short Bs[2][256 * 64];

    const int tid = threadIdx.x;
    const int lane = tid & 63;
    const int wid = tid >> 6;          // 0..7
    const int wm = wid >> 2;           // 0..1
    const int wn = wid & 3;            // 0..3
    const int lr = lane & 15;
    const int lg = lane >> 4;          // 0..3

    // XCD-aware swizzle (8 XCDs). 512 m-tiles x 4 n-tiles = 2048 blocks.
    const int g = blockIdx.x;
    const int xcd = g & 7;
    const int slot = g >> 3;                    // 0..255
    const int ntile = slot & 3;                 // 0..3
    const int mtile = xcd * 64 + (slot >> 2);   // 0..511
    const int m0 = mtile * 256;
    const int n0 = ntile * 256;
    const int bidx = m0 >> 11;         // 256-row tile never straddles a batch

    // A staging map: thread t -> rows (t>>3)+64*ci, 16B k-slot (t&7)
    const int ar = tid >> 3;           // 0..63
    const int as = tid & 7;            // 0..7

    f32x4 rs[8];   // single prefetch set: holds tile t+1's A across tile t

    auto loadA = [&](int kt) {
        const float* src = enc + (size_t)(m0 + ar) * Ee + kt * 64 + as * 8;
#pragma unroll
        for (int ci = 0; ci < 4; ++ci) {
            rs[ci * 2]     = *reinterpret_cast<const f32x4*>(src + (size_t)(64 * ci) * Ee);
            rs[ci * 2 + 1] = *reinterpret_cast<const f32x4*>(src + (size_t)(64 * ci) * Ee + 4);
        }
    };
    auto writeA = [&](int db) {
        char* abase = (char*)&As[db][0];
#pragma unroll
        for (int ci = 0; ci < 4; ++ci) {
            int r = ar + 64 * ci;
            u32x4 w;
            w.x = (unsigned)f2bf(rs[2 * ci].x) | ((unsigned)f2bf(rs[2 * ci].y) << 16);
            w.y = (unsigned)f2bf(rs[2 * ci].z) | ((unsigned)f2bf(rs[2 * ci].w) << 16);
            w.z = (unsigned)f2bf(rs[2 * ci + 1].x) | ((unsigned)f2bf(rs[2 * ci + 1].y) << 16);
            w.w = (unsigned)f2bf(rs[2 * ci + 1].z) | ((unsigned)f2bf(rs[2 * ci + 1].w) << 16);
            *reinterpret_cast<u32x4*>(abase + r * 128 + ((as * 16) ^ ((r & 7) << 4))) = w;
        }
    };
    // B direct-to-LDS: wave wid, call c writes LDS rows (wid*4+c)*8..+8 linearly;
    // lane l covers row +(l>>3), slot (l&7). Source slot pre-swizzled:
    // LDS slot s at row r holds global slot s^(r&7), r&7 == l>>3.
    auto stageB = [&](int kt, int db) {
        const int sg = (lane & 7) ^ (lane >> 3);
#pragma unroll
        for (int c = 0; c < 4; ++c) {
            int rr = (wid * 4 + c) * 8 + (lane >> 3);
            const unsigned short* src = w16t + (size_t)(n0 + rr) * Ee + kt * 64 + sg * 8;
            gload_lds16(src, &Bs[db][(wid * 4 + c) * 512]);
        }
    };

    // accumulators init with ddec
    f32x4 acc[8][4];
#pragma unroll
    for (int ni = 0; ni < 4; ++ni) {
        float dv = ddec[bidx * Hh + n0 + wn * 64 + ni * 16 + lr];
#pragma unroll
        for (int mi = 0; mi < 8; ++mi) {
            acc[mi][ni].x = dv; acc[mi][ni].y = dv;
            acc[mi][ni].z = dv; acc[mi][ni].w = dv;
        }
    }

    u32x4 af[4], bf[4];
    auto readB4 = [&](int db, int kh) {
        const char* bbase = (const char*)&Bs[db][0];
        const int kb = kh * 64 + lg * 16;
#pragma unroll
        for (int ni = 0; ni < 4; ++ni) {
            int r = wn * 64 + ni * 16 + lr;
            bf[ni] = *reinterpret_cast<const u32x4*>(bbase + r * 128 + (kb ^ ((r & 7) << 4)));
        }
    };
    auto readA4 = [&](int db, int kh, int mib) {
        const char* abase = (const char*)&As[db][0];
        const int kb = kh * 64 + lg * 16;
#pragma unroll
        for (int k = 0; k < 4; ++k) {
            int r = wm * 128 + (mib + k) * 16 + lr;
            af[k] = *reinterpret_cast<const u32x4*>(abase + r * 128 + (kb ^ ((r & 7) << 4)));
        }
    };
    auto mfma16 = [&](int mib) {
        __builtin_amdgcn_s_setprio(1);
#pragma unroll
        for (int k = 0; k < 4; ++k)
#pragma unroll
            for (int ni = 0; ni < 4; ++ni)
                asm("v_mfma_f32_16x16x32_bf16 %0, %1, %2, %0"
                    : "+v"(acc[mib + k][ni])
                    : "v"(af[k]), "v"(bf[ni]));
        __builtin_amdgcn_s_setprio(0);
    };

#define BARRIER() do { asm volatile("" ::: "memory"); \
    __builtin_amdgcn_s_barrier(); asm volatile("" ::: "memory"); } while (0)
#define LGKM0() asm volatile("s_waitcnt lgkmcnt(0)" ::: "memory")

    // ---- prologue ----
    loadA(0);
    writeA(0);                 // implicit vmcnt(0): loadA(0) complete
    LGKM0();                   // WAR fence: ds_writes drained before rs reuse
    stageB(0, 0);              // 4 gload_lds -> Bs[0]
    loadA(1);                  // 8 loads -> outstanding [B0(4), A1(8)]
    asm volatile("s_waitcnt vmcnt(8)" ::: "memory");  // B0 retired, A1 in flight
    BARRIER();

#pragma unroll 1
    for (int t = 0; t < 16; ++t) {
        const int p = t & 1;   // current LDS buffer (runtime: LDS addr only)
        // ---- phase A: kh=0, mi 0..3; issue next B staging ----
        readB4(p, 0);
        readA4(p, 0, 0);
        if (t < 15) stageB(t + 1, p ^ 1);   // 4 gload_lds (newest)
        BARRIER(); LGKM0();
        mfma16(0);
        BARRIER();
        // ---- phase B: kh=0, mi 4..7 ----
        readA4(p, 0, 4);
        BARRIER(); LGKM0();
        mfma16(4);
        BARRIER();
        // ---- phase C: kh=1, mi 0..3 ----
        readB4(p, 1);
        readA4(p, 1, 0);
        BARRIER(); LGKM0();
        mfma16(0);
        BARRIER();
        // ---- phase D: kh=1, mi 4..7; A cvt+ds_write; then (after the
        //      LGKM0 drains those ds_writes) overwrite rs with A(t+2) ----
        readA4(p, 1, 4);
        if (t < 15) writeA(p ^ 1);  // rs = tile t+1; implicit vmcnt(4):
                                    // A(t+1) done, B(t+1) stays in flight
        BARRIER(); LGKM0();         // publish writeA; WAR fence for rs
        if (t < 14) {
            loadA(t + 2);           // 8 loads -> outstanding [B(4), A(8)]
            asm volatile("s_waitcnt vmcnt(8)" ::: "memory");  // retire B only
        } else if (t == 14) {
            asm volatile("s_waitcnt vmcnt(0)" ::: "memory");  // tail: drain B15
        }
        mfma16(4);
        BARRIER();
    }

    // drain MFMA pipe before VALU reads of acc
    asm volatile("s_nop 7\n\ts_nop 7\n\ts_nop 7" ::: );

    float wout[4];
#pragma unroll
    for (int ni = 0; ni < 4; ++ni)
        wout[ni] = w_out[n0 + wn * 64 + ni * 16 + lr];

#pragma unroll
    for (int mi = 0; mi < 8; ++mi) {
#pragma unroll
        for (int i = 0; i < 4; ++i) {
            float s = 0.f;
#pragma unroll
            for (int ni = 0; ni < 4; ++ni) {
                float x = (i == 0) ? acc[mi][ni].x : (i == 1) ? acc[mi][ni].y
                           : (i == 2) ? acc[mi][ni].z : acc[mi][ni].w;
                // tanh(x) = 1 - 2/(e^{2x}+1)  (stable at +/-inf)
                float t = 1.f - 2.f / (__expf(2.f * x) + 1.f);
                s += t * wout[ni];
            }
            s += __shfl_xor(s, 1);
            s += __shfl_xor(s, 2);
            s += __shfl_xor(s, 4);
            s += __shfl_xor(s, 8);
            if (lr == 0) {
                int row = m0 + wm * 128 + mi * 16 + 4 * lg + i;
                atomicAdd(&scores[row], s);
            }
        }
    }
#undef BARRIER
#undef LGKM0
}

// ---------------------------------------------------------------------------
// K2: masked softmax over T per batch row, in place (scores -> probs).
// ---------------------------------------------------------------------------
__global__ __launch_bounds__(256) void softmax_kernel(float* __restrict__ sc,
                                                      const int* __restrict__ mask) {
    __shared__ float red[256];
    const int b = blockIdx.x;
    const int tid = threadIdx.x;
    float* row = sc + b * Tt;
    const int* mrow = mask + b * Tt;

    float v[8];
    float mx = -3.0e38f;
#pragma unroll
    for (int j = 0; j < 8; ++j) {
        int t = tid + j * 256;
        float s = row[t];
        v[j] = (mrow[t] == 0) ? -1.0e9f : s;
        mx = fmaxf(mx, v[j]);
    }
    red[tid] = mx;
    __syncthreads();
    for (int off = 128; off > 0; off >>= 1) {
        if (tid < off) red[tid] = fmaxf(red[tid], red[tid + off]);
        __syncthreads();
    }
    mx = red[0];
    __syncthreads();

    float p[8];
    float sum = 0.f;
#pragma unroll
    for (int j = 0; j < 8; ++j) {
        p[j] = __expf(v[j] - mx);   // masked -> exp(~-1e9) == 0 exactly
        sum += p[j];
    }
    red[tid] = sum;
    __syncthreads();
    for (int off = 128; off > 0; off >>= 1) {
        if (tid < off) red[tid] += red[tid + off];
        __syncthreads();
    }
    float inv = 1.f / red[0];
#pragma unroll
    for (int j = 0; j < 8; ++j)
        row[tid + j * 256] = p[j] * inv;
}

// ---------------------------------------------------------------------------
// K3: attn[b][e] = sum_t probs[b][t] * enc[b][t][e]   (memory bound)
// ---------------------------------------------------------------------------
__global__ __launch_bounds__(256) void attn_kernel(const float* __restrict__ enc,
                                                   const float* __restrict__ probs,
                                                   float* __restrict__ attn) {
    __shared__ float pr[128];
    const int b = blockIdx.y;
    const int tc = blockIdx.x;        // 0..15  t-chunk of 128
    const int tid = threadIdx.x;
    if (tid < 128) pr[tid] = probs[b * Tt + tc * 128 + tid];
    __syncthreads();

    const int e0 = tid * 4;
    f32x4 acc; acc.x = 0.f; acc.y = 0.f; acc.z = 0.f; acc.w = 0.f;
    const float* base = enc + (size_t)b * Tt * Ee + (size_t)tc * 128 * Ee + e0;
#pragma unroll 4
    for (int t = 0; t < 128; ++t) {
        f32x4 vv = *reinterpret_cast<const f32x4*>(base + (size_t)t * Ee);
        float pw = pr[t];
        acc.x += pw * vv.x; acc.y += pw * vv.y;
        acc.z += pw * vv.z; acc.w += pw * vv.w;
    }
    atomicAdd(&attn[b * Ee + e0 + 0], acc.x);
    atomicAdd(&attn[b * Ee + e0 + 1], acc.y);
    atomicAdd(&attn[b * Ee + e0 + 2], acc.z);
    atomicAdd(&attn[b * Ee + e0 + 3], acc.w);
}

// ---------------------------------------------------------------------------
extern "C" void kernel_launch(void* const* d_in, const int* in_sizes, int n_in,
                              void* d_out, int out_size, void* d_ws, size_t ws_size,
                              hipStream_t stream) {
    const float* enc      = (const float*)d_in[0];
    const float* dec      = (const float*)d_in[1];
    const int*   inp_mask = (const int*)d_in[2];
    const float* W_enc    = (const float*)d_in[3];
    const float* b_enc    = (const float*)d_in[4];
    const float* W_dec    = (const float*)d_in[5];
    const float* b_dec    = (const float*)d_in[6];
    const float* W_out    = (const float*)d_in[7];
    // b_out (d_in[8]) cancels in softmax and is otherwise unused.

    float* attn   = (float*)d_out;            // [64][1024]
    float* scores = (float*)d_out + ATTN_N;   // [64][2048], becomes probs

    unsigned short* w16t = (unsigned short*)d_ws;  // 2 MB bf16 W_enc^T
    // ddec [64][1024] fp32 lives temporarily in the attn region of d_out.
    float* ddec = attn;

    // zero score accumulator
    hipMemsetAsync(scores, 0, (size_t)PROB_N * sizeof(float), stream);

    wtrans_kernel<<<dim3(1024), 256, 0, stream>>>(W_enc, w16t);
    ddec_kernel<<<dim3(4, 64), 256, 0, stream>>>(dec, W_dec, b_dec, b_enc, ddec);
    gemm_score_kernel<<<dim3(2048), 512, 0, stream>>>(enc, w16t, ddec, W_out, scores);

    // attn region done serving as ddec; zero it for atomic accumulation
    hipMemsetAsync(attn, 0, (size_t)ATTN_N * sizeof(float), stream);

    softmax_kernel<<<dim3(64), 256, 0, stream>>>(scores, inp_mask);
    attn_kernel<<<dim3(16, 64), 256, 0, stream>>>(enc, scores, attn);
}

// Round 10
// 642.281 us; speedup vs baseline: 1.1659x; 1.0011x over previous
//
#include <hip/hip_runtime.h>
#include <hip/hip_bf16.h>

typedef __attribute__((ext_vector_type(4))) float f32x4;
typedef __attribute__((ext_vector_type(4))) unsigned int u32x4;
typedef __attribute__((ext_vector_type(8))) short s16x8;   // 8 bf16 = 4 VGPRs

// Problem constants
static constexpr int Bb = 64;
static constexpr int Tt = 2048;
static constexpr int Ee = 1024;
static constexpr int Hh = 1024;
static constexpr int ATTN_N = Bb * Ee;      // 65536
static constexpr int PROB_N = Bb * Tt;      // 131072

__device__ inline unsigned short f2bf(float f) {
    __hip_bfloat16 h = __float2bfloat16(f);  // RNE
    return __builtin_bit_cast(unsigned short, h);
}

__device__ inline void gload_lds16(const unsigned short* g, unsigned short* l) {
    __builtin_amdgcn_global_load_lds(
        (const __attribute__((address_space(1))) void*)g,
        (__attribute__((address_space(3))) void*)l,
        16, 0, 0);
}

// ---------------------------------------------------------------------------
// K0a: W_enc [E][H] fp32  ->  W16T [H][E] bf16 (transposed)
// ---------------------------------------------------------------------------
__global__ void wtrans_kernel(const float* __restrict__ w_enc,
                              unsigned short* __restrict__ w16t) {
    __shared__ float tile[32][33];
    const int bx = blockIdx.x & 31;   // h tile
    const int by = blockIdx.x >> 5;   // e tile
    const int tx = threadIdx.x & 31;
    const int ty = threadIdx.x >> 5;  // 0..7
#pragma unroll
    for (int j = 0; j < 4; ++j) {
        int e = by * 32 + ty + j * 8;
        int h = bx * 32 + tx;
        tile[ty + j * 8][tx] = w_enc[e * Hh + h];
    }
    __syncthreads();
#pragma unroll
    for (int j = 0; j < 4; ++j) {
        int h = bx * 32 + ty + j * 8;
        int e = by * 32 + tx;
        w16t[h * Ee + e] = f2bf(tile[tx][ty + j * 8]);
    }
}

// ---------------------------------------------------------------------------
// K0b: ddec[b][h] = dec[b]·W_dec[:,h] + b_dec[h] + b_enc[h]   (fp32 exact)
// ---------------------------------------------------------------------------
__global__ void ddec_kernel(const float* __restrict__ dec,
                            const float* __restrict__ w_dec,
                            const float* __restrict__ b_dec,
                            const float* __restrict__ b_enc,
                            float* __restrict__ ddec) {
    const int b = blockIdx.y;
    const int h = blockIdx.x * 256 + threadIdx.x;
    float acc = b_dec[h] + b_enc[h];
    const float* dr = dec + b * Ee;
#pragma unroll 4
    for (int e = 0; e < Ee; ++e) {
        acc += dr[e] * w_dec[e * Hh + h];
    }
    ddec[b * Hh + h] = acc;
}

// ---------------------------------------------------------------------------
// K1: fused  scores[b,t] += sum_h tanh(enc·W_enc + ddec) * W_out[h]
// 256x256 tile, BK=64, 8 waves (2M x 4N, per-wave 128x64).
// 4 phases per K-tile: {ds_read frags || staging issue} -> barrier ->
//   lgkmcnt(0) -> setprio(1) 16xMFMA setprio(0) -> barrier.
//
// R10 change (ONE variable vs the passing R9): MFMA via the
// __builtin_amdgcn_mfma_f32_16x16x32_bf16 intrinsic instead of inline asm.
// R1-R9 all used asm with "+v" (VGPR-class) constraints while the compiler
// allocated acc to AGPRs (evidence: VGPR_Count 116 < 128 floats of acc) --
// forcing v_accvgpr_read/write copies around EVERY mfma: ~512 VALU moves
// per K-tile per wave, the invariant ~560 TF ceiling across all schedules.
// The builtin lets MFMA consume/produce AGPR C/D directly (no copies).
//
// Pipeline (R9, passing): SINGLE A-prefetch register set rs[8];
// loadA(t+2) after phase-D "BARRIER; LGKM0" (WAR fence for rs);
// counted vmcnt (writeA implicit vmcnt(4); explicit vmcnt(8) retires B
// only; no vmcnt(0) in steady state). B staged via global_load_lds with
// inverse-swizzled source. XOR-swizzled LDS reads + XCD block swizzle.
// ---------------------------------------------------------------------------
__global__ __launch_bounds__(512, 1) void gemm_score_kernel(
    const float* __restrict__ enc, const unsigned short* __restrict__ w16t,
    const float* __restrict__ ddec, const float* __restrict__ w_out,
    float* __restrict__ scores) {
    __shared__ unsigned short As[2][256 * 64];
    __shared__ unsigned short Bs[2][256 * 64];

    const int tid = threadIdx.x;
    const int lane = tid & 63;
    const int wid = tid >> 6;          // 0..7
    const int wm = wid >> 2;           // 0..1
    const int wn = wid & 3;            // 0..3
    const int lr = lane & 15;
    const int lg = lane >> 4;          // 0..3

    // XCD-aware swizzle (8 XCDs). 512 m-tiles x 4 n-tiles = 2048 blocks.
    const int g = blockIdx.x;
    const int xcd = g & 7;
    const int slot = g >> 3;                    // 0..255
    const int ntile = slot & 3;                 // 0..3
    const int mtile = xcd * 64 + (slot >> 2);   // 0..511
    const int m0 = mtile * 256;
    const int n0 = ntile * 256;
    const int bidx = m0 >> 11;         // 256-row tile never straddles a batch

    // A staging map: thread t -> rows (t>>3)+64*ci, 16B k-slot (t&7)
    const int ar = tid >> 3;           // 0..63
    const int as = tid & 7;            // 0..7

    f32x4 rs[8];   // single prefetch set: holds tile t+1's A across tile t

    auto loadA = [&](int kt) {
        const float* src = enc + (size_t)(m0 + ar) * Ee + kt * 64 + as * 8;
#pragma unroll
        for (int ci = 0; ci < 4; ++ci) {
            rs[ci * 2]     = *reinterpret_cast<const f32x4*>(src + (size_t)(64 * ci) * Ee);
            rs[ci * 2 + 1] = *reinterpret_cast<const f32x4*>(src + (size_t)(64 * ci) * Ee + 4);
        }
    };
    auto writeA = [&](int db) {
        char* abase = (char*)&As[db][0];
#pragma unroll
        for (int ci = 0; ci < 4; ++ci) {
            int r = ar + 64 * ci;
            u32x4 w;
            w.x = (unsigned)f2bf(rs[2 * ci].x) | ((unsigned)f2bf(rs[2 * ci].y) << 16);
            w.y = (unsigned)f2bf(rs[2 * ci].z) | ((unsigned)f2bf(rs[2 * ci].w) << 16);
            w.z = (unsigned)f2bf(rs[2 * ci + 1].x) | ((unsigned)f2bf(rs[2 * ci + 1].y) << 16);
            w.w = (unsigned)f2bf(rs[2 * ci + 1].z) | ((unsigned)f2bf(rs[2 * ci + 1].w) << 16);
            *reinterpret_cast<u32x4*>(abase + r * 128 + ((as * 16) ^ ((r & 7) << 4))) = w;
        }
    };
    // B direct-to-LDS: wave wid, call c writes LDS rows (wid*4+c)*8..+8 linearly;
    // lane l covers row +(l>>3), slot (l&7). Source slot pre-swizzled:
    // LDS slot s at row r holds global slot s^(r&7), r&7 == l>>3.
    auto stageB = [&](int kt, int db) {
        const int sg = (lane & 7) ^ (lane >> 3);
#pragma unroll
        for (int c = 0; c < 4; ++c) {
            int rr = (wid * 4 + c) * 8 + (lane >> 3);
            const unsigned short* src = w16t + (size_t)(n0 + rr) * Ee + kt * 64 + sg * 8;
            gload_lds16(src, &Bs[db][(wid * 4 + c) * 512]);
        }
    };

    // accumulators init with ddec
    f32x4 acc[8][4];
#pragma unroll
    for (int ni = 0; ni < 4; ++ni) {
        float dv = ddec[bidx * Hh + n0 + wn * 64 + ni * 16 + lr];
#pragma unroll
        for (int mi = 0; mi < 8; ++mi) {
            acc[mi][ni].x = dv; acc[mi][ni].y = dv;
            acc[mi][ni].z = dv; acc[mi][ni].w = dv;
        }
    }

    u32x4 af[4], bf[4];
    auto readB4 = [&](int db, int kh) {
        const char* bbase = (const char*)&Bs[db][0];
        const int kb = kh * 64 + lg * 16;
#pragma unroll
        for (int ni = 0; ni < 4; ++ni) {
            int r = wn * 64 + ni * 16 + lr;
            bf[ni] = *reinterpret_cast<const u32x4*>(bbase + r * 128 + (kb ^ ((r & 7) << 4)));
        }
    };
    auto readA4 = [&](int db, int kh, int mib) {
        const char* abase = (const char*)&As[db][0];
        const int kb = kh * 64 + lg * 16;
#pragma unroll
        for (int k = 0; k < 4; ++k) {
            int r = wm * 128 + (mib + k) * 16 + lr;
            af[k] = *reinterpret_cast<const u32x4*>(abase + r * 128 + (kb ^ ((r & 7) << 4)));
        }
    };
    auto mfma16 = [&](int mib) {
        __builtin_amdgcn_s_setprio(1);
#pragma unroll
        for (int k = 0; k < 4; ++k)
#pragma unroll
            for (int ni = 0; ni < 4; ++ni)
                acc[mib + k][ni] = __builtin_amdgcn_mfma_f32_16x16x32_bf16(
                    __builtin_bit_cast(s16x8, af[k]),
                    __builtin_bit_cast(s16x8, bf[ni]),
                    acc[mib + k][ni], 0, 0, 0);
        __builtin_amdgcn_s_setprio(0);
    };

#define BARRIER() do { asm volatile("" ::: "memory"); \
    __builtin_amdgcn_s_barrier(); asm volatile("" ::: "memory"); } while (0)
#define LGKM0() asm volatile("s_waitcnt lgkmcnt(0)" ::: "memory")

    // ---- prologue ----
    loadA(0);
    writeA(0);                 // implicit vmcnt(0): loadA(0) complete
    LGKM0();                   // WAR fence: ds_writes drained before rs reuse
    stageB(0, 0);              // 4 gload_lds -> Bs[0]
    loadA(1);                  // 8 loads -> outstanding [B0(4), A1(8)]
    asm volatile("s_waitcnt vmcnt(8)" ::: "memory");  // B0 retired, A1 in flight
    BARRIER();

#pragma unroll 1
    for (int t = 0; t < 16; ++t) {
        const int p = t & 1;   // current LDS buffer (runtime: LDS addr only)
        // ---- phase A: kh=0, mi 0..3; issue next B staging ----
        readB4(p, 0);
        readA4(p, 0, 0);
        if (t < 15) stageB(t + 1, p ^ 1);   // 4 gload_lds (newest)
        BARRIER(); LGKM0();
        mfma16(0);
        BARRIER();
        // ---- phase B: kh=0, mi 4..7 ----
        readA4(p, 0, 4);
        BARRIER(); LGKM0();
        mfma16(4);
        BARRIER();
        // ---- phase C: kh=1, mi 0..3 ----
        readB4(p, 1);
        readA4(p, 1, 0);
        BARRIER(); LGKM0();
        mfma16(0);
        BARRIER();
        // ---- phase D: kh=1, mi 4..7; A cvt+ds_write; then (after the
        //      LGKM0 drains those ds_writes) overwrite rs with A(t+2) ----
        readA4(p, 1, 4);
        if (t < 15) writeA(p ^ 1);  // rs = tile t+1; implicit vmcnt(4):
                                    // A(t+1) done, B(t+1) stays in flight
        BARRIER(); LGKM0();         // publish writeA; WAR fence for rs
        if (t < 14) {
            loadA(t + 2);           // 8 loads -> outstanding [B(4), A(8)]
            asm volatile("s_waitcnt vmcnt(8)" ::: "memory");  // retire B only
        } else if (t == 14) {
            asm volatile("s_waitcnt vmcnt(0)" ::: "memory");  // tail: drain B15
        }
        mfma16(4);
        BARRIER();
    }

    float wout[4];
#pragma unroll
    for (int ni = 0; ni < 4; ++ni)
        wout[ni] = w_out[n0 + wn * 64 + ni * 16 + lr];

#pragma unroll
    for (int mi = 0; mi < 8; ++mi) {
#pragma unroll
        for (int i = 0; i < 4; ++i) {
            float s = 0.f;
#pragma unroll
            for (int ni = 0; ni < 4; ++ni) {
                float x = (i == 0) ? acc[mi][ni].x : (i == 1) ? acc[mi][ni].y
                           : (i == 2) ? acc[mi][ni].z : acc[mi][ni].w;
                // tanh(x) = 1 - 2/(e^{2x}+1)  (stable at +/-inf)
                float t = 1.f - 2.f / (__expf(2.f * x) + 1.f);
                s += t * wout[ni];
            }
            s += __shfl_xor(s, 1);
            s += __shfl_xor(s, 2);
            s += __shfl_xor(s, 4);
            s += __shfl_xor(s, 8);
            if (lr == 0) {
                int row = m0 + wm * 128 + mi * 16 + 4 * lg + i;
                atomicAdd(&scores[row], s);
            }
        }
    }
#undef BARRIER
#undef LGKM0
}

// ---------------------------------------------------------------------------
// K2: masked softmax over T per batch row, in place (scores -> probs).
// ---------------------------------------------------------------------------
__global__ __launch_bounds__(256) void softmax_kernel(float* __restrict__ sc,
                                                      const int* __restrict__ mask) {
    __shared__ float red[256];
    const int b = blockIdx.x;
    const int tid = threadIdx.x;
    float* row = sc + b * Tt;
    const int* mrow = mask + b * Tt;

    float v[8];
    float mx = -3.0e38f;
#pragma unroll
    for (int j = 0; j < 8; ++j) {
        int t = tid + j * 256;
        float s = row[t];
        v[j] = (mrow[t] == 0) ? -1.0e9f : s;
        mx = fmaxf(mx, v[j]);
    }
    red[tid] = mx;
    __syncthreads();
    for (int off = 128; off > 0; off >>= 1) {
        if (tid < off) red[tid] = fmaxf(red[tid], red[tid + off]);
        __syncthreads();
    }
    mx = red[0];
    __syncthreads();

    float p[8];
    float sum = 0.f;
#pragma unroll
    for (int j = 0; j < 8; ++j) {
        p[j] = __expf(v[j] - mx);   // masked -> exp(~-1e9) == 0 exactly
        sum += p[j];
    }
    red[tid] = sum;
    __syncthreads();
    for (int off = 128; off > 0; off >>= 1) {
        if (tid < off) red[tid] += red[tid + off];
        __syncthreads();
    }
    float inv = 1.f / red[0];
#pragma unroll
    for (int j = 0; j < 8; ++j)
        row[tid + j * 256] = p[j] * inv;
}

// ---------------------------------------------------------------------------
// K3: attn[b][e] = sum_t probs[b][t] * enc[b][t][e]   (memory bound)
// ---------------------------------------------------------------------------
__global__ __launch_bounds__(256) void attn_kernel(const float* __restrict__ enc,
                                                   const float* __restrict__ probs,
                                                   float* __restrict__ attn) {
    __shared__ float pr[128];
    const int b = blockIdx.y;
    const int tc = blockIdx.x;        // 0..15  t-chunk of 128
    const int tid = threadIdx.x;
    if (tid < 128) pr[tid] = probs[b * Tt + tc * 128 + tid];
    __syncthreads();

    const int e0 = tid * 4;
    f32x4 acc; acc.x = 0.f; acc.y = 0.f; acc.z = 0.f; acc.w = 0.f;
    const float* base = enc + (size_t)b * Tt * Ee + (size_t)tc * 128 * Ee + e0;
#pragma unroll 4
    for (int t = 0; t < 128; ++t) {
        f32x4 vv = *reinterpret_cast<const f32x4*>(base + (size_t)t * Ee);
        float pw = pr[t];
        acc.x += pw * vv.x; acc.y += pw * vv.y;
        acc.z += pw * vv.z; acc.w += pw * vv.w;
    }
    atomicAdd(&attn[b * Ee + e0 + 0], acc.x);
    atomicAdd(&attn[b * Ee + e0 + 1], acc.y);
    atomicAdd(&attn[b * Ee + e0 + 2], acc.z);
    atomicAdd(&attn[b * Ee + e0 + 3], acc.w);
}

// ---------------------------------------------------------------------------
extern "C" void kernel_launch(void* const* d_in, const int* in_sizes, int n_in,
                              void* d_out, int out_size, void* d_ws, size_t ws_size,
                              hipStream_t stream) {
    const float* enc      = (const float*)d_in[0];
    const float* dec      = (const float*)d_in[1];
    const int*   inp_mask = (const int*)d_in[2];
    const float* W_enc    = (const float*)d_in[3];
    const float* b_enc    = (const float*)d_in[4];
    const float* W_dec    = (const float*)d_in[5];
    const float* b_dec    = (const float*)d_in[6];
    const float* W_out    = (const float*)d_in[7];
    // b_out (d_in[8]) cancels in softmax and is otherwise unused.

    float* attn   = (float*)d_out;            // [64][1024]
    float* scores = (float*)d_out + ATTN_N;   // [64][2048], becomes probs

    unsigned short* w16t = (unsigned short*)d_ws;  // 2 MB bf16 W_enc^T
    // ddec [64][1024] fp32 lives temporarily in the attn region of d_out.
    float* ddec = attn;

    // zero score accumulator
    hipMemsetAsync(scores, 0, (size_t)PROB_N * sizeof(float), stream);

    wtrans_kernel<<<dim3(1024), 256, 0, stream>>>(W_enc, w16t);
    ddec_kernel<<<dim3(4, 64), 256, 0, stream>>>(dec, W_dec, b_dec, b_enc, ddec);
    gemm_score_kernel<<<dim3(2048), 512, 0, stream>>>(enc, w16t, ddec, W_out, scores);

    // attn region done serving as ddec; zero it for atomic accumulation
    hipMemsetAsync(attn, 0, (size_t)ATTN_N * sizeof(float), stream);

    softmax_kernel<<<dim3(64), 256, 0, stream>>>(scores, inp_mask);
    attn_kernel<<<dim3(16, 64), 256, 0, stream>>>(enc, scores, attn);
}